// Round 1
// baseline (988.555 us; speedup 1.0000x reference)
//
#include <hip/hip_runtime.h>
#include <math.h>

#define NN 100000
#define EE 1600000
#define NEG 0.2f

__device__ __forceinline__ float lrelu(float v) { return v > 0.f ? v : NEG * v; }

// ---------------- GEMM1: h1 = x @ W1 (no bias), fused a_src1/a_dst1 ----------------
// block = 256 threads = 32 fg (8 features each) x 8 ng (4 nodes each) -> 32 nodes/block
__global__ __launch_bounds__(256) void gemm1_kernel(
    const float* __restrict__ x, const float* __restrict__ W1,
    const float* __restrict__ attS1, const float* __restrict__ attD1,
    float* __restrict__ h1, float* __restrict__ asrc1, float* __restrict__ adst1)
{
    __shared__ float xs[128][36];   // transposed x tile, padded (16B-aligned rows of 144B)
    const int tid  = threadIdx.x;
    const int base = blockIdx.x * 32;

    for (int t = tid; t < 32 * 128; t += 256) {
        int node = t >> 7, k = t & 127;
        xs[k][node] = x[(size_t)(base + node) * 128 + k];
    }
    __syncthreads();

    const int fg = tid & 31;   // features fg*8 .. fg*8+7
    const int ng = tid >> 5;   // nodes   ng*4 .. ng*4+3

    float acc[4][8];
#pragma unroll
    for (int i = 0; i < 4; i++) {
#pragma unroll
        for (int c = 0; c < 8; c++) acc[i][c] = 0.f;
    }

    const float* wbase = W1 + fg * 8;
    for (int k = 0; k < 128; k++) {
        float4 xv = *(const float4*)&xs[k][ng * 4];
        float4 w0 = *(const float4*)(wbase + k * 256);
        float4 w1 = *(const float4*)(wbase + k * 256 + 4);
        float xa[4] = {xv.x, xv.y, xv.z, xv.w};
        float wa[8] = {w0.x, w0.y, w0.z, w0.w, w1.x, w1.y, w1.z, w1.w};
#pragma unroll
        for (int i = 0; i < 4; i++) {
#pragma unroll
            for (int c = 0; c < 8; c++)
                acc[i][c] = fmaf(xa[i], wa[c], acc[i][c]);
        }
    }

    float attS[8], attD[8];
#pragma unroll
    for (int c = 0; c < 8; c++) { attS[c] = attS1[fg * 8 + c]; attD[c] = attD1[fg * 8 + c]; }
    const int head = fg >> 3;

#pragma unroll
    for (int i = 0; i < 4; i++) {
        int node = base + ng * 4 + i;
        *(float4*)&h1[(size_t)node * 256 + fg * 8]     = make_float4(acc[i][0], acc[i][1], acc[i][2], acc[i][3]);
        *(float4*)&h1[(size_t)node * 256 + fg * 8 + 4] = make_float4(acc[i][4], acc[i][5], acc[i][6], acc[i][7]);
        float ps = 0.f, pd = 0.f;
#pragma unroll
        for (int c = 0; c < 8; c++) { ps = fmaf(acc[i][c], attS[c], ps); pd = fmaf(acc[i][c], attD[c], pd); }
        ps += __shfl_xor(ps, 1); ps += __shfl_xor(ps, 2); ps += __shfl_xor(ps, 4);
        pd += __shfl_xor(pd, 1); pd += __shfl_xor(pd, 2); pd += __shfl_xor(pd, 4);
        if ((fg & 7) == 0) { asrc1[node * 4 + head] = ps; adst1[node * 4 + head] = pd; }
    }
}

// ---------------- CSR build ----------------
__global__ void hist_kernel(const int* __restrict__ ei, int* __restrict__ counts)
{
    int e = blockIdx.x * 256 + threadIdx.x;
    if (e >= EE) return;
    atomicAdd(&counts[ei[EE + e]], 1);
}

// single-block exclusive scan over NN counts -> offs[NN+1]
__global__ void scan_kernel(const int* __restrict__ counts, int* __restrict__ offs)
{
    __shared__ int part[256];
    const int tid = threadIdx.x;
    const int chunk = (NN + 255) / 256;
    int lo = tid * chunk;
    int hi = lo + chunk; if (hi > NN) hi = NN;
    int s = 0;
    for (int i = lo; i < hi; i++) s += counts[i];
    part[tid] = s;
    __syncthreads();
    for (int off = 1; off < 256; off <<= 1) {
        int v = (tid >= off) ? part[tid - off] : 0;
        __syncthreads();
        part[tid] += v;
        __syncthreads();
    }
    int base = (tid == 0) ? 0 : part[tid - 1];
    for (int i = lo; i < hi; i++) { offs[i] = base; base += counts[i]; }
    if (tid == 255) offs[NN] = base;
}

// scatter edges into CSR slots; fuse per-edge attention weight computation
__global__ void scatter_kernel(const int* __restrict__ ei,
                               const float* __restrict__ asrc1, const float* __restrict__ adst1,
                               int* __restrict__ cursor, int* __restrict__ csr_src,
                               float* __restrict__ ewp)
{
    int e = blockIdx.x * 256 + threadIdx.x;
    if (e >= EE) return;
    int s = ei[e], d = ei[EE + e];
    int pos = atomicAdd(&cursor[d], 1);
    csr_src[pos] = s;
    float4 as = *(const float4*)&asrc1[(size_t)s * 4];
    float4 ad = *(const float4*)&adst1[(size_t)d * 4];
    float4 w;
    w.x = expf(lrelu(as.x + ad.x));
    w.y = expf(lrelu(as.y + ad.y));
    w.z = expf(lrelu(as.z + ad.z));
    w.w = expf(lrelu(as.w + ad.w));
    *(float4*)&ewp[(size_t)pos * 4] = w;
}

// ---------------- layer-1 aggregation: one wave per destination node ----------------
__global__ __launch_bounds__(256) void agg1_kernel(
    const int* __restrict__ offs, const int* __restrict__ csr_src,
    const float* __restrict__ ewp, const float* __restrict__ h1,
    float* __restrict__ g1)
{
    int wid  = (blockIdx.x * 256 + threadIdx.x) >> 6;  // node
    int lane = threadIdx.x & 63;
    if (wid >= NN) return;
    int lo = offs[wid], hi = offs[wid + 1];
    int head = lane >> 4;                              // features lane*4..+3 all in head lane>>4
    float a0 = 0.f, a1 = 0.f, a2 = 0.f, a3 = 0.f, wsum = 0.f;
    for (int idx = lo; idx < hi; ++idx) {
        int s = csr_src[idx];
        float w = ewp[(size_t)idx * 4 + head];
        float4 hv = *(const float4*)&h1[(size_t)s * 256 + lane * 4];
        a0 = fmaf(w, hv.x, a0);
        a1 = fmaf(w, hv.y, a1);
        a2 = fmaf(w, hv.z, a2);
        a3 = fmaf(w, hv.w, a3);
        wsum += w;
    }
    float inv = 1.f / (wsum + 1e-16f);
    *(float4*)&g1[(size_t)wid * 256 + lane * 4] = make_float4(a0 * inv, a1 * inv, a2 * inv, a3 * inv);
}

// ---------------- node2: bias + BN + ELU + GEMM2(256->2) + att2 dots (wave/node) ----------------
__global__ __launch_bounds__(256) void node2_kernel(
    const float* __restrict__ g1, const float* __restrict__ b1,
    const float* __restrict__ gamma, const float* __restrict__ beta,
    const float* __restrict__ rmean, const float* __restrict__ rvar,
    const float* __restrict__ W2, const float* __restrict__ attS2, const float* __restrict__ attD2,
    float* __restrict__ h2, float* __restrict__ asrc2, float* __restrict__ adst2)
{
    int n    = blockIdx.x * 4 + (threadIdx.x >> 6);
    int lane = threadIdx.x & 63;
    if (n >= NN) return;
    int f4 = lane * 4;
    float4 v  = *(const float4*)&g1[(size_t)n * 256 + f4];
    float4 bv = *(const float4*)&b1[f4];
    float4 rm = *(const float4*)&rmean[f4];
    float4 rv = *(const float4*)&rvar[f4];
    float4 gm = *(const float4*)&gamma[f4];
    float4 bt = *(const float4*)&beta[f4];
    float va[4] = {v.x, v.y, v.z, v.w};
    float ba[4] = {bv.x, bv.y, bv.z, bv.w};
    float rma[4] = {rm.x, rm.y, rm.z, rm.w};
    float rva[4] = {rv.x, rv.y, rv.z, rv.w};
    float gma[4] = {gm.x, gm.y, gm.z, gm.w};
    float bta[4] = {bt.x, bt.y, bt.z, bt.w};
    float t[4];
#pragma unroll
    for (int j = 0; j < 4; j++) {
        float u = (va[j] + ba[j] - rma[j]) * rsqrtf(rva[j] + 1e-5f) * gma[j] + bta[j];
        t[j] = u > 0.f ? u : expm1f(u);
    }
    float4 w01 = *(const float4*)&W2[(size_t)f4 * 2];
    float4 w23 = *(const float4*)&W2[(size_t)f4 * 2 + 4];
    float c0 = t[0] * w01.x + t[1] * w01.z + t[2] * w23.x + t[3] * w23.z;
    float c1 = t[0] * w01.y + t[1] * w01.w + t[2] * w23.y + t[3] * w23.w;
    for (int off = 1; off < 64; off <<= 1) {
        c0 += __shfl_xor(c0, off);
        c1 += __shfl_xor(c1, off);
    }
    if (lane == 0) {
        h2[(size_t)n * 2]     = c0;
        h2[(size_t)n * 2 + 1] = c1;
        asrc2[n] = c0 * attS2[0] + c1 * attS2[1];
        adst2[n] = c0 * attD2[0] + c1 * attD2[1];
    }
}

// ---------------- layer-2 edge pass: accumulate numerator + denominator ----------------
__global__ void edge2_kernel(const int* __restrict__ ei,
                             const float* __restrict__ asrc2, const float* __restrict__ adst2,
                             const float* __restrict__ h2,
                             float* __restrict__ num2, float* __restrict__ s2)
{
    int e = blockIdx.x * 256 + threadIdx.x;
    if (e >= EE) return;
    int s = ei[e], d = ei[EE + e];
    float w = expf(lrelu(asrc2[s] + adst2[d]));
    float2 hv = *(const float2*)&h2[(size_t)s * 2];
    atomicAdd(&num2[(size_t)d * 2],     w * hv.x);
    atomicAdd(&num2[(size_t)d * 2 + 1], w * hv.y);
    atomicAdd(&s2[d], w);
}

// ---------------- final: bias + log_softmax over 2 classes ----------------
__global__ void final_kernel(const float* __restrict__ num2, const float* __restrict__ s2,
                             const float* __restrict__ b2, float* __restrict__ out)
{
    int n = blockIdx.x * 256 + threadIdx.x;
    if (n >= NN) return;
    float inv = 1.f / (s2[n] + 1e-16f);
    float v0 = num2[(size_t)n * 2] * inv + b2[0];
    float v1 = num2[(size_t)n * 2 + 1] * inv + b2[1];
    float m = fmaxf(v0, v1);
    float lse = m + log1pf(expf(fminf(v0, v1) - m));
    out[(size_t)n * 2]     = v0 - lse;
    out[(size_t)n * 2 + 1] = v1 - lse;
}

extern "C" void kernel_launch(void* const* d_in, const int* in_sizes, int n_in,
                              void* d_out, int out_size, void* d_ws, size_t ws_size,
                              hipStream_t stream)
{
    const float* x     = (const float*)d_in[0];
    const int*   ei    = (const int*)d_in[1];
    const float* W1    = (const float*)d_in[2];
    const float* attS1 = (const float*)d_in[3];
    const float* attD1 = (const float*)d_in[4];
    const float* b1    = (const float*)d_in[5];
    const float* gamma = (const float*)d_in[6];
    const float* beta  = (const float*)d_in[7];
    const float* rmean = (const float*)d_in[8];
    const float* rvar  = (const float*)d_in[9];
    const float* W2    = (const float*)d_in[10];
    const float* attS2 = (const float*)d_in[11];
    const float* attD2 = (const float*)d_in[12];
    const float* b2    = (const float*)d_in[13];
    float* out = (float*)d_out;

    // workspace layout (floats then ints)
    float* f = (float*)d_ws;
    float* h1    = f;                       // N*256
    float* asrc1 = h1    + (size_t)NN * 256;  // N*4
    float* adst1 = asrc1 + (size_t)NN * 4;    // N*4
    float* g1    = adst1 + (size_t)NN * 4;    // N*256
    float* ewp   = g1    + (size_t)NN * 256;  // E*4
    float* h2    = ewp   + (size_t)EE * 4;    // N*2
    float* asrc2 = h2    + (size_t)NN * 2;    // N
    float* adst2 = asrc2 + (size_t)NN;        // N
    float* num2  = adst2 + (size_t)NN;        // N*2  [zeroed]
    float* s2    = num2  + (size_t)NN * 2;    // N    [zeroed]
    int* counts  = (int*)(s2 + (size_t)NN);   // N    [zeroed]
    int* offs    = counts + NN;               // N+1
    int* cursor  = offs + (NN + 1);           // N
    int* csr_src = cursor + NN;               // E

    // zero: num2, s2, counts are contiguous
    hipMemsetAsync(num2, 0, (size_t)NN * 4 * sizeof(float), stream);

    gemm1_kernel<<<NN / 32, 256, 0, stream>>>(x, W1, attS1, attD1, h1, asrc1, adst1);

    hist_kernel<<<(EE + 255) / 256, 256, 0, stream>>>(ei, counts);
    scan_kernel<<<1, 256, 0, stream>>>(counts, offs);
    hipMemcpyAsync(cursor, offs, (size_t)NN * sizeof(int), hipMemcpyDeviceToDevice, stream);
    scatter_kernel<<<(EE + 255) / 256, 256, 0, stream>>>(ei, asrc1, adst1, cursor, csr_src, ewp);

    agg1_kernel<<<(NN + 3) / 4, 256, 0, stream>>>(offs, csr_src, ewp, h1, g1);

    node2_kernel<<<(NN + 3) / 4, 256, 0, stream>>>(g1, b1, gamma, beta, rmean, rvar,
                                                   W2, attS2, attD2, h2, asrc2, adst2);

    edge2_kernel<<<(EE + 255) / 256, 256, 0, stream>>>(ei, asrc2, adst2, h2, num2, s2);

    final_kernel<<<(NN + 255) / 256, 256, 0, stream>>>(num2, s2, b2, out);
}

// Round 2
// 774.358 us; speedup vs baseline: 1.2766x; 1.2766x over previous
//
#include <hip/hip_runtime.h>
#include <math.h>

#define NN 100000
#define EE 1600000
#define NEG 0.2f

__device__ __forceinline__ float lrelu(float v) { return v > 0.f ? v : NEG * v; }

// ---------------- GEMM1: h1 = x @ W1 (no bias), fused a_src1/a_dst1 ----------------
// block = 256 threads = 32 fg (8 features each) x 8 ng (4 nodes each) -> 32 nodes/block
__global__ __launch_bounds__(256) void gemm1_kernel(
    const float* __restrict__ x, const float* __restrict__ W1,
    const float* __restrict__ attS1, const float* __restrict__ attD1,
    float* __restrict__ h1, float* __restrict__ asrc1, float* __restrict__ adst1)
{
    __shared__ float xs[128][36];   // transposed x tile, padded
    const int tid  = threadIdx.x;
    const int base = blockIdx.x * 32;

    for (int t = tid; t < 32 * 128; t += 256) {
        int node = t >> 7, k = t & 127;
        xs[k][node] = x[(size_t)(base + node) * 128 + k];
    }
    __syncthreads();

    const int fg = tid & 31;   // features fg*8 .. fg*8+7
    const int ng = tid >> 5;   // nodes   ng*4 .. ng*4+3

    float acc[4][8];
#pragma unroll
    for (int i = 0; i < 4; i++) {
#pragma unroll
        for (int c = 0; c < 8; c++) acc[i][c] = 0.f;
    }

    const float* wbase = W1 + fg * 8;
    for (int k = 0; k < 128; k++) {
        float4 xv = *(const float4*)&xs[k][ng * 4];
        float4 w0 = *(const float4*)(wbase + k * 256);
        float4 w1 = *(const float4*)(wbase + k * 256 + 4);
        float xa[4] = {xv.x, xv.y, xv.z, xv.w};
        float wa[8] = {w0.x, w0.y, w0.z, w0.w, w1.x, w1.y, w1.z, w1.w};
#pragma unroll
        for (int i = 0; i < 4; i++) {
#pragma unroll
            for (int c = 0; c < 8; c++)
                acc[i][c] = fmaf(xa[i], wa[c], acc[i][c]);
        }
    }

    float attS[8], attD[8];
#pragma unroll
    for (int c = 0; c < 8; c++) { attS[c] = attS1[fg * 8 + c]; attD[c] = attD1[fg * 8 + c]; }
    const int head = fg >> 3;

#pragma unroll
    for (int i = 0; i < 4; i++) {
        int node = base + ng * 4 + i;
        *(float4*)&h1[(size_t)node * 256 + fg * 8]     = make_float4(acc[i][0], acc[i][1], acc[i][2], acc[i][3]);
        *(float4*)&h1[(size_t)node * 256 + fg * 8 + 4] = make_float4(acc[i][4], acc[i][5], acc[i][6], acc[i][7]);
        float ps = 0.f, pd = 0.f;
#pragma unroll
        for (int c = 0; c < 8; c++) { ps = fmaf(acc[i][c], attS[c], ps); pd = fmaf(acc[i][c], attD[c], pd); }
        ps += __shfl_xor(ps, 1); ps += __shfl_xor(ps, 2); ps += __shfl_xor(ps, 4);
        pd += __shfl_xor(pd, 1); pd += __shfl_xor(pd, 2); pd += __shfl_xor(pd, 4);
        if ((fg & 7) == 0) { asrc1[node * 4 + head] = ps; adst1[node * 4 + head] = pd; }
    }
}

// ---------------- CSR build ----------------
__global__ void hist_kernel(const int* __restrict__ ei, int* __restrict__ counts)
{
    int e = blockIdx.x * 256 + threadIdx.x;
    if (e >= EE) return;
    atomicAdd(&counts[ei[EE + e]], 1);
}

// single-block exclusive scan over NN counts -> offs[NN+1]
__global__ void scan_kernel(const int* __restrict__ counts, int* __restrict__ offs)
{
    __shared__ int part[256];
    const int tid = threadIdx.x;
    const int chunk = (NN + 255) / 256;
    int lo = tid * chunk;
    int hi = lo + chunk; if (hi > NN) hi = NN;
    int s = 0;
    for (int i = lo; i < hi; i++) s += counts[i];
    part[tid] = s;
    __syncthreads();
    for (int off = 1; off < 256; off <<= 1) {
        int v = (tid >= off) ? part[tid - off] : 0;
        __syncthreads();
        part[tid] += v;
        __syncthreads();
    }
    int base = (tid == 0) ? 0 : part[tid - 1];
    for (int i = lo; i < hi; i++) { offs[i] = base; base += counts[i]; }
    if (tid == 255) offs[NN] = base;
}

// scatter edges into CSR slots; fuse per-edge attention weight computation
__global__ void scatter_kernel(const int* __restrict__ ei,
                               const float* __restrict__ asrc1, const float* __restrict__ adst1,
                               int* __restrict__ cursor, int* __restrict__ csr_src,
                               float* __restrict__ ewp)
{
    int e = blockIdx.x * 256 + threadIdx.x;
    if (e >= EE) return;
    int s = ei[e], d = ei[EE + e];
    int pos = atomicAdd(&cursor[d], 1);
    csr_src[pos] = s;
    float4 as = *(const float4*)&asrc1[(size_t)s * 4];
    float4 ad = *(const float4*)&adst1[(size_t)d * 4];
    float4 w;
    w.x = expf(lrelu(as.x + ad.x));
    w.y = expf(lrelu(as.y + ad.y));
    w.z = expf(lrelu(as.z + ad.z));
    w.w = expf(lrelu(as.w + ad.w));
    *(float4*)&ewp[(size_t)pos * 4] = w;
}

// ---------------- layer-1 aggregation: one wave per destination node ----------------
__global__ __launch_bounds__(256) void agg1_kernel(
    const int* __restrict__ offs, const int* __restrict__ csr_src,
    const float* __restrict__ ewp, const float* __restrict__ h1,
    float* __restrict__ g1)
{
    int wid  = (blockIdx.x * 256 + threadIdx.x) >> 6;  // node
    int lane = threadIdx.x & 63;
    if (wid >= NN) return;
    int lo = offs[wid], hi = offs[wid + 1];
    int head = lane >> 4;                              // features lane*4..+3 all in head lane>>4
    float a0 = 0.f, a1 = 0.f, a2 = 0.f, a3 = 0.f, wsum = 0.f;
    for (int idx = lo; idx < hi; ++idx) {
        int s = csr_src[idx];
        float w = ewp[(size_t)idx * 4 + head];
        float4 hv = *(const float4*)&h1[(size_t)s * 256 + lane * 4];
        a0 = fmaf(w, hv.x, a0);
        a1 = fmaf(w, hv.y, a1);
        a2 = fmaf(w, hv.z, a2);
        a3 = fmaf(w, hv.w, a3);
        wsum += w;
    }
    float inv = 1.f / (wsum + 1e-16f);
    *(float4*)&g1[(size_t)wid * 256 + lane * 4] = make_float4(a0 * inv, a1 * inv, a2 * inv, a3 * inv);
}

// ---------------- node2: bias + BN + ELU + GEMM2(256->2) + att2 dots (wave/node) ----------------
__global__ __launch_bounds__(256) void node2_kernel(
    const float* __restrict__ g1, const float* __restrict__ b1,
    const float* __restrict__ gamma, const float* __restrict__ beta,
    const float* __restrict__ rmean, const float* __restrict__ rvar,
    const float* __restrict__ W2, const float* __restrict__ attS2, const float* __restrict__ attD2,
    float* __restrict__ h2, float* __restrict__ asrc2, float* __restrict__ adst2)
{
    int n    = blockIdx.x * 4 + (threadIdx.x >> 6);
    int lane = threadIdx.x & 63;
    if (n >= NN) return;
    int f4 = lane * 4;
    float4 v  = *(const float4*)&g1[(size_t)n * 256 + f4];
    float4 bv = *(const float4*)&b1[f4];
    float4 rm = *(const float4*)&rmean[f4];
    float4 rv = *(const float4*)&rvar[f4];
    float4 gm = *(const float4*)&gamma[f4];
    float4 bt = *(const float4*)&beta[f4];
    float va[4] = {v.x, v.y, v.z, v.w};
    float ba[4] = {bv.x, bv.y, bv.z, bv.w};
    float rma[4] = {rm.x, rm.y, rm.z, rm.w};
    float rva[4] = {rv.x, rv.y, rv.z, rv.w};
    float gma[4] = {gm.x, gm.y, gm.z, gm.w};
    float bta[4] = {bt.x, bt.y, bt.z, bt.w};
    float t[4];
#pragma unroll
    for (int j = 0; j < 4; j++) {
        float u = (va[j] + ba[j] - rma[j]) * rsqrtf(rva[j] + 1e-5f) * gma[j] + bta[j];
        t[j] = u > 0.f ? u : expm1f(u);
    }
    float4 w01 = *(const float4*)&W2[(size_t)f4 * 2];
    float4 w23 = *(const float4*)&W2[(size_t)f4 * 2 + 4];
    float c0 = t[0] * w01.x + t[1] * w01.z + t[2] * w23.x + t[3] * w23.z;
    float c1 = t[0] * w01.y + t[1] * w01.w + t[2] * w23.y + t[3] * w23.w;
    for (int off = 1; off < 64; off <<= 1) {
        c0 += __shfl_xor(c0, off);
        c1 += __shfl_xor(c1, off);
    }
    if (lane == 0) {
        h2[(size_t)n * 2]     = c0;
        h2[(size_t)n * 2 + 1] = c1;
        asrc2[n] = c0 * attS2[0] + c1 * attS2[1];
        adst2[n] = c0 * attD2[0] + c1 * attD2[1];
    }
}

// ---------------- layer-2 aggregation via CSR + fused bias/log_softmax ----------------
// one thread per destination node; h2 (800 KB) and asrc2 (400 KB) are L2-resident
__global__ void agg2_kernel(const int* __restrict__ offs, const int* __restrict__ csr_src,
                            const float* __restrict__ asrc2, const float* __restrict__ adst2,
                            const float* __restrict__ h2, const float* __restrict__ b2,
                            float* __restrict__ out)
{
    int n = blockIdx.x * 256 + threadIdx.x;
    if (n >= NN) return;
    int lo = offs[n], hi = offs[n + 1];
    float ad = adst2[n];
    float n0 = 0.f, n1 = 0.f, ws = 0.f;
    for (int i = lo; i < hi; ++i) {
        int s = csr_src[i];
        float w = expf(lrelu(asrc2[s] + ad));
        float2 hv = *(const float2*)&h2[(size_t)s * 2];
        n0 = fmaf(w, hv.x, n0);
        n1 = fmaf(w, hv.y, n1);
        ws += w;
    }
    float inv = 1.f / (ws + 1e-16f);
    float v0 = n0 * inv + b2[0];
    float v1 = n1 * inv + b2[1];
    float m = fmaxf(v0, v1);
    float lse = m + log1pf(expf(fminf(v0, v1) - m));
    out[(size_t)n * 2]     = v0 - lse;
    out[(size_t)n * 2 + 1] = v1 - lse;
}

extern "C" void kernel_launch(void* const* d_in, const int* in_sizes, int n_in,
                              void* d_out, int out_size, void* d_ws, size_t ws_size,
                              hipStream_t stream)
{
    const float* x     = (const float*)d_in[0];
    const int*   ei    = (const int*)d_in[1];
    const float* W1    = (const float*)d_in[2];
    const float* attS1 = (const float*)d_in[3];
    const float* attD1 = (const float*)d_in[4];
    const float* b1    = (const float*)d_in[5];
    const float* gamma = (const float*)d_in[6];
    const float* beta  = (const float*)d_in[7];
    const float* rmean = (const float*)d_in[8];
    const float* rvar  = (const float*)d_in[9];
    const float* W2    = (const float*)d_in[10];
    const float* attS2 = (const float*)d_in[11];
    const float* attD2 = (const float*)d_in[12];
    const float* b2    = (const float*)d_in[13];
    float* out = (float*)d_out;

    // workspace layout (floats then ints)
    float* f = (float*)d_ws;
    float* h1    = f;                         // N*256
    float* asrc1 = h1    + (size_t)NN * 256;  // N*4
    float* adst1 = asrc1 + (size_t)NN * 4;    // N*4
    float* g1    = adst1 + (size_t)NN * 4;    // N*256
    float* ewp   = g1    + (size_t)NN * 256;  // E*4
    float* h2    = ewp   + (size_t)EE * 4;    // N*2
    float* asrc2 = h2    + (size_t)NN * 2;    // N
    float* adst2 = asrc2 + (size_t)NN;        // N
    int* counts  = (int*)(adst2 + (size_t)NN); // N [zeroed]
    int* offs    = counts + NN;               // N+1
    int* cursor  = offs + (NN + 1);           // N
    int* csr_src = cursor + NN;               // E

    hipMemsetAsync(counts, 0, (size_t)NN * sizeof(int), stream);

    gemm1_kernel<<<NN / 32, 256, 0, stream>>>(x, W1, attS1, attD1, h1, asrc1, adst1);

    hist_kernel<<<(EE + 255) / 256, 256, 0, stream>>>(ei, counts);
    scan_kernel<<<1, 256, 0, stream>>>(counts, offs);
    hipMemcpyAsync(cursor, offs, (size_t)NN * sizeof(int), hipMemcpyDeviceToDevice, stream);
    scatter_kernel<<<(EE + 255) / 256, 256, 0, stream>>>(ei, asrc1, adst1, cursor, csr_src, ewp);

    agg1_kernel<<<(NN + 3) / 4, 256, 0, stream>>>(offs, csr_src, ewp, h1, g1);

    node2_kernel<<<(NN + 3) / 4, 256, 0, stream>>>(g1, b1, gamma, beta, rmean, rvar,
                                                   W2, attS2, attD2, h2, asrc2, adst2);

    agg2_kernel<<<(NN + 255) / 256, 256, 0, stream>>>(offs, csr_src, asrc2, adst2, h2, b2, out);
}

// Round 3
// 638.107 us; speedup vs baseline: 1.5492x; 1.2135x over previous
//
#include <hip/hip_runtime.h>
#include <hip/hip_fp16.h>
#include <math.h>

#define NN 100000
#define EE 1600000
#define NEG 0.2f

__device__ __forceinline__ float lrelu(float v) { return v > 0.f ? v : NEG * v; }

// ---------------- GEMM1: h1 = x @ W1 (no bias), fused a_src1/a_dst1 ----------------
// block = 256 threads = 32 fg (8 features each) x 8 ng (4 nodes each) -> 32 nodes/block
// h1 stored as fp16 (halves the aggregation gather traffic); att logits stay fp32.
__global__ __launch_bounds__(256) void gemm1_kernel(
    const float* __restrict__ x, const float* __restrict__ W1,
    const float* __restrict__ attS1, const float* __restrict__ attD1,
    __half* __restrict__ h1, float* __restrict__ asrc1, float* __restrict__ adst1)
{
    __shared__ float xs[128][36];   // transposed x tile, padded
    const int tid  = threadIdx.x;
    const int base = blockIdx.x * 32;

    for (int t = tid; t < 32 * 128; t += 256) {
        int node = t >> 7, k = t & 127;
        xs[k][node] = x[(size_t)(base + node) * 128 + k];
    }
    __syncthreads();

    const int fg = tid & 31;   // features fg*8 .. fg*8+7
    const int ng = tid >> 5;   // nodes   ng*4 .. ng*4+3

    float acc[4][8];
#pragma unroll
    for (int i = 0; i < 4; i++) {
#pragma unroll
        for (int c = 0; c < 8; c++) acc[i][c] = 0.f;
    }

    const float* wbase = W1 + fg * 8;
    for (int k = 0; k < 128; k++) {
        float4 xv = *(const float4*)&xs[k][ng * 4];
        float4 w0 = *(const float4*)(wbase + k * 256);
        float4 w1 = *(const float4*)(wbase + k * 256 + 4);
        float xa[4] = {xv.x, xv.y, xv.z, xv.w};
        float wa[8] = {w0.x, w0.y, w0.z, w0.w, w1.x, w1.y, w1.z, w1.w};
#pragma unroll
        for (int i = 0; i < 4; i++) {
#pragma unroll
            for (int c = 0; c < 8; c++)
                acc[i][c] = fmaf(xa[i], wa[c], acc[i][c]);
        }
    }

    float attS[8], attD[8];
#pragma unroll
    for (int c = 0; c < 8; c++) { attS[c] = attS1[fg * 8 + c]; attD[c] = attD1[fg * 8 + c]; }
    const int head = fg >> 3;

#pragma unroll
    for (int i = 0; i < 4; i++) {
        int node = base + ng * 4 + i;
        __half hb[8];
#pragma unroll
        for (int c = 0; c < 8; c++) hb[c] = __float2half(acc[i][c]);
        *(float4*)&h1[(size_t)node * 256 + fg * 8] = *(float4*)hb;   // 16B packed fp16 store
        float ps = 0.f, pd = 0.f;
#pragma unroll
        for (int c = 0; c < 8; c++) { ps = fmaf(acc[i][c], attS[c], ps); pd = fmaf(acc[i][c], attD[c], pd); }
        ps += __shfl_xor(ps, 1); ps += __shfl_xor(ps, 2); ps += __shfl_xor(ps, 4);
        pd += __shfl_xor(pd, 1); pd += __shfl_xor(pd, 2); pd += __shfl_xor(pd, 4);
        if ((fg & 7) == 0) { asrc1[node * 4 + head] = ps; adst1[node * 4 + head] = pd; }
    }
}

// ---------------- CSR build ----------------
__global__ void hist_kernel(const int* __restrict__ ei, int* __restrict__ counts)
{
    int e = blockIdx.x * 256 + threadIdx.x;
    if (e >= EE) return;
    atomicAdd(&counts[ei[EE + e]], 1);
}

// single-block exclusive scan over NN counts -> offs[NN+1]
__global__ void scan_kernel(const int* __restrict__ counts, int* __restrict__ offs)
{
    __shared__ int part[256];
    const int tid = threadIdx.x;
    const int chunk = (NN + 255) / 256;
    int lo = tid * chunk;
    int hi = lo + chunk; if (hi > NN) hi = NN;
    int s = 0;
    for (int i = lo; i < hi; i++) s += counts[i];
    part[tid] = s;
    __syncthreads();
    for (int off = 1; off < 256; off <<= 1) {
        int v = (tid >= off) ? part[tid - off] : 0;
        __syncthreads();
        part[tid] += v;
        __syncthreads();
    }
    int base = (tid == 0) ? 0 : part[tid - 1];
    for (int i = lo; i < hi; i++) { offs[i] = base; base += counts[i]; }
    if (tid == 255) offs[NN] = base;
}

// scatter edges into CSR slots; fuse per-edge attention weight computation
__global__ void scatter_kernel(const int* __restrict__ ei,
                               const float* __restrict__ asrc1, const float* __restrict__ adst1,
                               int* __restrict__ cursor, int* __restrict__ csr_src,
                               float* __restrict__ ewp)
{
    int e = blockIdx.x * 256 + threadIdx.x;
    if (e >= EE) return;
    int s = ei[e], d = ei[EE + e];
    int pos = atomicAdd(&cursor[d], 1);
    csr_src[pos] = s;
    float4 as = *(const float4*)&asrc1[(size_t)s * 4];
    float4 ad = *(const float4*)&adst1[(size_t)d * 4];
    float4 w;
    w.x = expf(lrelu(as.x + ad.x));
    w.y = expf(lrelu(as.y + ad.y));
    w.z = expf(lrelu(as.z + ad.z));
    w.w = expf(lrelu(as.w + ad.w));
    *(float4*)&ewp[(size_t)pos * 4] = w;
}

// ---------------- layer-1 aggregation: one wave per destination node ----------------
// gathers fp16 h1 rows (512 B/edge); 2-way unrolled for memory-level parallelism
__global__ __launch_bounds__(256) void agg1_kernel(
    const int* __restrict__ offs, const int* __restrict__ csr_src,
    const float* __restrict__ ewp, const __half* __restrict__ h1,
    float* __restrict__ g1)
{
    int wid  = (blockIdx.x * 256 + threadIdx.x) >> 6;  // node
    int lane = threadIdx.x & 63;
    if (wid >= NN) return;
    int lo = offs[wid], hi = offs[wid + 1];
    int head = lane >> 4;                              // features lane*4..+3 all in head lane>>4
    float a0 = 0.f, a1 = 0.f, a2 = 0.f, a3 = 0.f, wsum = 0.f;

    int idx = lo;
    for (; idx + 1 < hi; idx += 2) {
        int s0 = csr_src[idx];
        int s1 = csr_src[idx + 1];
        float w0 = ewp[(size_t)idx * 4 + head];
        float w1 = ewp[(size_t)(idx + 1) * 4 + head];
        uint2 r0 = *(const uint2*)(h1 + (size_t)s0 * 256 + lane * 4);
        uint2 r1 = *(const uint2*)(h1 + (size_t)s1 * 256 + lane * 4);
        float2 f00 = __half22float2(*(const __half2*)&r0.x);
        float2 f01 = __half22float2(*(const __half2*)&r0.y);
        float2 f10 = __half22float2(*(const __half2*)&r1.x);
        float2 f11 = __half22float2(*(const __half2*)&r1.y);
        a0 = fmaf(w0, f00.x, a0); a1 = fmaf(w0, f00.y, a1);
        a2 = fmaf(w0, f01.x, a2); a3 = fmaf(w0, f01.y, a3);
        a0 = fmaf(w1, f10.x, a0); a1 = fmaf(w1, f10.y, a1);
        a2 = fmaf(w1, f11.x, a2); a3 = fmaf(w1, f11.y, a3);
        wsum += w0 + w1;
    }
    if (idx < hi) {
        int s0 = csr_src[idx];
        float w0 = ewp[(size_t)idx * 4 + head];
        uint2 r0 = *(const uint2*)(h1 + (size_t)s0 * 256 + lane * 4);
        float2 f00 = __half22float2(*(const __half2*)&r0.x);
        float2 f01 = __half22float2(*(const __half2*)&r0.y);
        a0 = fmaf(w0, f00.x, a0); a1 = fmaf(w0, f00.y, a1);
        a2 = fmaf(w0, f01.x, a2); a3 = fmaf(w0, f01.y, a3);
        wsum += w0;
    }

    float inv = 1.f / (wsum + 1e-16f);
    *(float4*)&g1[(size_t)wid * 256 + lane * 4] = make_float4(a0 * inv, a1 * inv, a2 * inv, a3 * inv);
}

// ---------------- node2: bias + BN + ELU + GEMM2(256->2) + att2 dots (wave/node) ----------------
__global__ __launch_bounds__(256) void node2_kernel(
    const float* __restrict__ g1, const float* __restrict__ b1,
    const float* __restrict__ gamma, const float* __restrict__ beta,
    const float* __restrict__ rmean, const float* __restrict__ rvar,
    const float* __restrict__ W2, const float* __restrict__ attS2, const float* __restrict__ attD2,
    float* __restrict__ h2, float* __restrict__ asrc2, float* __restrict__ adst2)
{
    int n    = blockIdx.x * 4 + (threadIdx.x >> 6);
    int lane = threadIdx.x & 63;
    if (n >= NN) return;
    int f4 = lane * 4;
    float4 v  = *(const float4*)&g1[(size_t)n * 256 + f4];
    float4 bv = *(const float4*)&b1[f4];
    float4 rm = *(const float4*)&rmean[f4];
    float4 rv = *(const float4*)&rvar[f4];
    float4 gm = *(const float4*)&gamma[f4];
    float4 bt = *(const float4*)&beta[f4];
    float va[4] = {v.x, v.y, v.z, v.w};
    float ba[4] = {bv.x, bv.y, bv.z, bv.w};
    float rma[4] = {rm.x, rm.y, rm.z, rm.w};
    float rva[4] = {rv.x, rv.y, rv.z, rv.w};
    float gma[4] = {gm.x, gm.y, gm.z, gm.w};
    float bta[4] = {bt.x, bt.y, bt.z, bt.w};
    float t[4];
#pragma unroll
    for (int j = 0; j < 4; j++) {
        float u = (va[j] + ba[j] - rma[j]) * rsqrtf(rva[j] + 1e-5f) * gma[j] + bta[j];
        t[j] = u > 0.f ? u : expm1f(u);
    }
    float4 w01 = *(const float4*)&W2[(size_t)f4 * 2];
    float4 w23 = *(const float4*)&W2[(size_t)f4 * 2 + 4];
    float c0 = t[0] * w01.x + t[1] * w01.z + t[2] * w23.x + t[3] * w23.z;
    float c1 = t[0] * w01.y + t[1] * w01.w + t[2] * w23.y + t[3] * w23.w;
    for (int off = 1; off < 64; off <<= 1) {
        c0 += __shfl_xor(c0, off);
        c1 += __shfl_xor(c1, off);
    }
    if (lane == 0) {
        h2[(size_t)n * 2]     = c0;
        h2[(size_t)n * 2 + 1] = c1;
        asrc2[n] = c0 * attS2[0] + c1 * attS2[1];
        adst2[n] = c0 * attD2[0] + c1 * attD2[1];
    }
}

// ---------------- layer-2 aggregation via CSR + fused bias/log_softmax ----------------
// one thread per destination node; h2 (800 KB) and asrc2 (400 KB) are L2-resident
__global__ void agg2_kernel(const int* __restrict__ offs, const int* __restrict__ csr_src,
                            const float* __restrict__ asrc2, const float* __restrict__ adst2,
                            const float* __restrict__ h2, const float* __restrict__ b2,
                            float* __restrict__ out)
{
    int n = blockIdx.x * 256 + threadIdx.x;
    if (n >= NN) return;
    int lo = offs[n], hi = offs[n + 1];
    float ad = adst2[n];
    float n0 = 0.f, n1 = 0.f, ws = 0.f;
    for (int i = lo; i < hi; ++i) {
        int s = csr_src[i];
        float w = expf(lrelu(asrc2[s] + ad));
        float2 hv = *(const float2*)&h2[(size_t)s * 2];
        n0 = fmaf(w, hv.x, n0);
        n1 = fmaf(w, hv.y, n1);
        ws += w;
    }
    float inv = 1.f / (ws + 1e-16f);
    float v0 = n0 * inv + b2[0];
    float v1 = n1 * inv + b2[1];
    float m = fmaxf(v0, v1);
    float lse = m + log1pf(expf(fminf(v0, v1) - m));
    out[(size_t)n * 2]     = v0 - lse;
    out[(size_t)n * 2 + 1] = v1 - lse;
}

extern "C" void kernel_launch(void* const* d_in, const int* in_sizes, int n_in,
                              void* d_out, int out_size, void* d_ws, size_t ws_size,
                              hipStream_t stream)
{
    const float* x     = (const float*)d_in[0];
    const int*   ei    = (const int*)d_in[1];
    const float* W1    = (const float*)d_in[2];
    const float* attS1 = (const float*)d_in[3];
    const float* attD1 = (const float*)d_in[4];
    const float* b1    = (const float*)d_in[5];
    const float* gamma = (const float*)d_in[6];
    const float* beta  = (const float*)d_in[7];
    const float* rmean = (const float*)d_in[8];
    const float* rvar  = (const float*)d_in[9];
    const float* W2    = (const float*)d_in[10];
    const float* attS2 = (const float*)d_in[11];
    const float* attD2 = (const float*)d_in[12];
    const float* b2    = (const float*)d_in[13];
    float* out = (float*)d_out;

    // workspace layout
    float* f = (float*)d_ws;
    float* asrc1 = f;                         // N*4
    float* adst1 = asrc1 + (size_t)NN * 4;    // N*4
    float* g1    = adst1 + (size_t)NN * 4;    // N*256
    float* ewp   = g1    + (size_t)NN * 256;  // E*4
    float* h2    = ewp   + (size_t)EE * 4;    // N*2
    float* asrc2 = h2    + (size_t)NN * 2;    // N
    float* adst2 = asrc2 + (size_t)NN;        // N
    int* counts  = (int*)(adst2 + (size_t)NN); // N [zeroed]
    int* offs    = counts + NN;               // N+1
    int* cursor  = offs + (NN + 1);           // N
    int* csr_src = cursor + NN;               // E
    __half* h1   = (__half*)(csr_src + EE);   // N*256 fp16

    hipMemsetAsync(counts, 0, (size_t)NN * sizeof(int), stream);

    gemm1_kernel<<<NN / 32, 256, 0, stream>>>(x, W1, attS1, attD1, h1, asrc1, adst1);

    hist_kernel<<<(EE + 255) / 256, 256, 0, stream>>>(ei, counts);
    scan_kernel<<<1, 256, 0, stream>>>(counts, offs);
    hipMemcpyAsync(cursor, offs, (size_t)NN * sizeof(int), hipMemcpyDeviceToDevice, stream);
    scatter_kernel<<<(EE + 255) / 256, 256, 0, stream>>>(ei, asrc1, adst1, cursor, csr_src, ewp);

    agg1_kernel<<<(NN + 3) / 4, 256, 0, stream>>>(offs, csr_src, ewp, h1, g1);

    node2_kernel<<<(NN + 3) / 4, 256, 0, stream>>>(g1, b1, gamma, beta, rmean, rvar,
                                                   W2, attS2, attD2, h2, asrc2, adst2);

    agg2_kernel<<<(NN + 255) / 256, 256, 0, stream>>>(offs, csr_src, asrc2, adst2, h2, b2, out);
}

// Round 4
// 497.726 us; speedup vs baseline: 1.9861x; 1.2820x over previous
//
#include <hip/hip_runtime.h>
#include <hip/hip_fp16.h>
#include <math.h>

#define NN 100000
#define EE 1600000
#define NEG 0.2f
#define NB 98   // ceil(NN/1024) scan blocks

__device__ __forceinline__ float lrelu(float v) { return v > 0.f ? v : NEG * v; }

// ---------------- GEMM1: h1 = x @ W1 (no bias), fused a_src1/a_dst1 ----------------
__global__ __launch_bounds__(256) void gemm1_kernel(
    const float* __restrict__ x, const float* __restrict__ W1,
    const float* __restrict__ attS1, const float* __restrict__ attD1,
    __half* __restrict__ h1, float* __restrict__ asrc1, float* __restrict__ adst1)
{
    __shared__ float xs[128][36];   // transposed x tile, padded
    const int tid  = threadIdx.x;
    const int base = blockIdx.x * 32;

    for (int t = tid; t < 32 * 128; t += 256) {
        int node = t >> 7, k = t & 127;
        xs[k][node] = x[(size_t)(base + node) * 128 + k];
    }
    __syncthreads();

    const int fg = tid & 31;   // features fg*8 .. fg*8+7
    const int ng = tid >> 5;   // nodes   ng*4 .. ng*4+3

    float acc[4][8];
#pragma unroll
    for (int i = 0; i < 4; i++) {
#pragma unroll
        for (int c = 0; c < 8; c++) acc[i][c] = 0.f;
    }

    const float* wbase = W1 + fg * 8;
    for (int k = 0; k < 128; k++) {
        float4 xv = *(const float4*)&xs[k][ng * 4];
        float4 w0 = *(const float4*)(wbase + k * 256);
        float4 w1 = *(const float4*)(wbase + k * 256 + 4);
        float xa[4] = {xv.x, xv.y, xv.z, xv.w};
        float wa[8] = {w0.x, w0.y, w0.z, w0.w, w1.x, w1.y, w1.z, w1.w};
#pragma unroll
        for (int i = 0; i < 4; i++) {
#pragma unroll
            for (int c = 0; c < 8; c++)
                acc[i][c] = fmaf(xa[i], wa[c], acc[i][c]);
        }
    }

    float attS[8], attD[8];
#pragma unroll
    for (int c = 0; c < 8; c++) { attS[c] = attS1[fg * 8 + c]; attD[c] = attD1[fg * 8 + c]; }
    const int head = fg >> 3;

#pragma unroll
    for (int i = 0; i < 4; i++) {
        int node = base + ng * 4 + i;
        __half hb[8];
#pragma unroll
        for (int c = 0; c < 8; c++) hb[c] = __float2half(acc[i][c]);
        *(float4*)&h1[(size_t)node * 256 + fg * 8] = *(float4*)hb;   // 16B packed fp16 store
        float ps = 0.f, pd = 0.f;
#pragma unroll
        for (int c = 0; c < 8; c++) { ps = fmaf(acc[i][c], attS[c], ps); pd = fmaf(acc[i][c], attD[c], pd); }
        ps += __shfl_xor(ps, 1); ps += __shfl_xor(ps, 2); ps += __shfl_xor(ps, 4);
        pd += __shfl_xor(pd, 1); pd += __shfl_xor(pd, 2); pd += __shfl_xor(pd, 4);
        if ((fg & 7) == 0) { asrc1[node * 4 + head] = ps; adst1[node * 4 + head] = pd; }
    }
}

// ---------------- CSR build ----------------
__global__ void hist_kernel(const int* __restrict__ ei, int* __restrict__ counts)
{
    int e = blockIdx.x * 256 + threadIdx.x;
    if (e >= EE) return;
    atomicAdd(&counts[ei[EE + e]], 1);
}

// phase 1: per-block (1024 elements) reduce -> bsum
__global__ __launch_bounds__(256) void scan1_kernel(const int* __restrict__ counts, int* __restrict__ bsum)
{
    __shared__ int red[256];
    int t = threadIdx.x;
    int i0 = blockIdx.x * 1024 + t * 4;
    int s = 0;
    if (i0 + 3 < NN) {
        int4 v = *(const int4*)&counts[i0];
        s = v.x + v.y + v.z + v.w;
    } else {
#pragma unroll
        for (int j = 0; j < 4; j++) { int i = i0 + j; if (i < NN) s += counts[i]; }
    }
    red[t] = s;
    __syncthreads();
    for (int off = 128; off > 0; off >>= 1) {
        if (t < off) red[t] += red[t + off];
        __syncthreads();
    }
    if (t == 0) bsum[blockIdx.x] = red[0];
}

// phase 2: single small block scans NB block sums -> exclusive bases; writes offs[NN]
__global__ void scan2_kernel(const int* __restrict__ bsum, int* __restrict__ bbase, int* __restrict__ offs)
{
    __shared__ int sh[128];
    int t = threadIdx.x;
    int v = (t < NB) ? bsum[t] : 0;
    sh[t] = v;
    __syncthreads();
    for (int off = 1; off < 128; off <<= 1) {
        int u = (t >= off) ? sh[t - off] : 0;
        __syncthreads();
        sh[t] += u;
        __syncthreads();
    }
    if (t < NB) bbase[t] = sh[t] - v;   // exclusive
    if (t == 0) offs[NN] = EE;
}

// phase 3: per-block exclusive scan of its 1024 counts + base -> offs
__global__ __launch_bounds__(256) void scan3_kernel(const int* __restrict__ counts,
                                                    const int* __restrict__ bbase,
                                                    int* __restrict__ offs)
{
    __shared__ int sh[256];
    int t = threadIdx.x;
    int i0 = blockIdx.x * 1024 + t * 4;
    int c[4];
    int s = 0;
#pragma unroll
    for (int j = 0; j < 4; j++) { int i = i0 + j; c[j] = (i < NN) ? counts[i] : 0; s += c[j]; }
    sh[t] = s;
    __syncthreads();
    for (int off = 1; off < 256; off <<= 1) {
        int u = (t >= off) ? sh[t - off] : 0;
        __syncthreads();
        sh[t] += u;
        __syncthreads();
    }
    int run = bbase[blockIdx.x] + sh[t] - s;   // exclusive within block
    if (i0 + 3 < NN) {
        int4 o;
        o.x = run; run += c[0];
        o.y = run; run += c[1];
        o.z = run; run += c[2];
        o.w = run;
        *(int4*)&offs[i0] = o;
    } else {
#pragma unroll
        for (int j = 0; j < 4; j++) { int i = i0 + j; if (i < NN) { offs[i] = run; run += c[j]; } }
    }
}

// scatter edges into CSR slots; fuse per-edge attention weight computation
__global__ void scatter_kernel(const int* __restrict__ ei,
                               const float* __restrict__ asrc1, const float* __restrict__ adst1,
                               int* __restrict__ cursor, int* __restrict__ csr_src,
                               float* __restrict__ ewp)
{
    int e = blockIdx.x * 256 + threadIdx.x;
    if (e >= EE) return;
    int s = ei[e], d = ei[EE + e];
    int pos = atomicAdd(&cursor[d], 1);
    csr_src[pos] = s;
    float4 as = *(const float4*)&asrc1[(size_t)s * 4];
    float4 ad = *(const float4*)&adst1[(size_t)d * 4];
    float4 w;
    w.x = expf(lrelu(as.x + ad.x));
    w.y = expf(lrelu(as.y + ad.y));
    w.z = expf(lrelu(as.z + ad.z));
    w.w = expf(lrelu(as.w + ad.w));
    *(float4*)&ewp[(size_t)pos * 4] = w;
}

// ---------------- layer-1 aggregation: one wave per destination node ----------------
__global__ __launch_bounds__(256) void agg1_kernel(
    const int* __restrict__ offs, const int* __restrict__ csr_src,
    const float* __restrict__ ewp, const __half* __restrict__ h1,
    float* __restrict__ g1)
{
    int wid  = (blockIdx.x * 256 + threadIdx.x) >> 6;  // node
    int lane = threadIdx.x & 63;
    if (wid >= NN) return;
    int lo = offs[wid], hi = offs[wid + 1];
    int head = lane >> 4;
    float a0 = 0.f, a1 = 0.f, a2 = 0.f, a3 = 0.f, wsum = 0.f;

    int idx = lo;
    for (; idx + 1 < hi; idx += 2) {
        int s0 = csr_src[idx];
        int s1 = csr_src[idx + 1];
        float w0 = ewp[(size_t)idx * 4 + head];
        float w1 = ewp[(size_t)(idx + 1) * 4 + head];
        uint2 r0 = *(const uint2*)(h1 + (size_t)s0 * 256 + lane * 4);
        uint2 r1 = *(const uint2*)(h1 + (size_t)s1 * 256 + lane * 4);
        float2 f00 = __half22float2(*(const __half2*)&r0.x);
        float2 f01 = __half22float2(*(const __half2*)&r0.y);
        float2 f10 = __half22float2(*(const __half2*)&r1.x);
        float2 f11 = __half22float2(*(const __half2*)&r1.y);
        a0 = fmaf(w0, f00.x, a0); a1 = fmaf(w0, f00.y, a1);
        a2 = fmaf(w0, f01.x, a2); a3 = fmaf(w0, f01.y, a3);
        a0 = fmaf(w1, f10.x, a0); a1 = fmaf(w1, f10.y, a1);
        a2 = fmaf(w1, f11.x, a2); a3 = fmaf(w1, f11.y, a3);
        wsum += w0 + w1;
    }
    if (idx < hi) {
        int s0 = csr_src[idx];
        float w0 = ewp[(size_t)idx * 4 + head];
        uint2 r0 = *(const uint2*)(h1 + (size_t)s0 * 256 + lane * 4);
        float2 f00 = __half22float2(*(const __half2*)&r0.x);
        float2 f01 = __half22float2(*(const __half2*)&r0.y);
        a0 = fmaf(w0, f00.x, a0); a1 = fmaf(w0, f00.y, a1);
        a2 = fmaf(w0, f01.x, a2); a3 = fmaf(w0, f01.y, a3);
        wsum += w0;
    }

    float inv = 1.f / (wsum + 1e-16f);
    *(float4*)&g1[(size_t)wid * 256 + lane * 4] = make_float4(a0 * inv, a1 * inv, a2 * inv, a3 * inv);
}

// ---------------- node2: bias + BN + ELU + GEMM2(256->2) + att2 dots (wave/node) ----------------
__global__ __launch_bounds__(256) void node2_kernel(
    const float* __restrict__ g1, const float* __restrict__ b1,
    const float* __restrict__ gamma, const float* __restrict__ beta,
    const float* __restrict__ rmean, const float* __restrict__ rvar,
    const float* __restrict__ W2, const float* __restrict__ attS2, const float* __restrict__ attD2,
    float* __restrict__ h2, float* __restrict__ asrc2, float* __restrict__ adst2)
{
    int n    = blockIdx.x * 4 + (threadIdx.x >> 6);
    int lane = threadIdx.x & 63;
    if (n >= NN) return;
    int f4 = lane * 4;
    float4 v  = *(const float4*)&g1[(size_t)n * 256 + f4];
    float4 bv = *(const float4*)&b1[f4];
    float4 rm = *(const float4*)&rmean[f4];
    float4 rv = *(const float4*)&rvar[f4];
    float4 gm = *(const float4*)&gamma[f4];
    float4 bt = *(const float4*)&beta[f4];
    float va[4] = {v.x, v.y, v.z, v.w};
    float ba[4] = {bv.x, bv.y, bv.z, bv.w};
    float rma[4] = {rm.x, rm.y, rm.z, rm.w};
    float rva[4] = {rv.x, rv.y, rv.z, rv.w};
    float gma[4] = {gm.x, gm.y, gm.z, gm.w};
    float bta[4] = {bt.x, bt.y, bt.z, bt.w};
    float t[4];
#pragma unroll
    for (int j = 0; j < 4; j++) {
        float u = (va[j] + ba[j] - rma[j]) * rsqrtf(rva[j] + 1e-5f) * gma[j] + bta[j];
        t[j] = u > 0.f ? u : expm1f(u);
    }
    float4 w01 = *(const float4*)&W2[(size_t)f4 * 2];
    float4 w23 = *(const float4*)&W2[(size_t)f4 * 2 + 4];
    float c0 = t[0] * w01.x + t[1] * w01.z + t[2] * w23.x + t[3] * w23.z;
    float c1 = t[0] * w01.y + t[1] * w01.w + t[2] * w23.y + t[3] * w23.w;
    for (int off = 1; off < 64; off <<= 1) {
        c0 += __shfl_xor(c0, off);
        c1 += __shfl_xor(c1, off);
    }
    if (lane == 0) {
        h2[(size_t)n * 2]     = c0;
        h2[(size_t)n * 2 + 1] = c1;
        asrc2[n] = c0 * attS2[0] + c1 * attS2[1];
        adst2[n] = c0 * attD2[0] + c1 * attD2[1];
    }
}

// ---------------- layer-2 aggregation via CSR + fused bias/log_softmax ----------------
__global__ void agg2_kernel(const int* __restrict__ offs, const int* __restrict__ csr_src,
                            const float* __restrict__ asrc2, const float* __restrict__ adst2,
                            const float* __restrict__ h2, const float* __restrict__ b2,
                            float* __restrict__ out)
{
    int n = blockIdx.x * 256 + threadIdx.x;
    if (n >= NN) return;
    int lo = offs[n], hi = offs[n + 1];
    float ad = adst2[n];
    float n0 = 0.f, n1 = 0.f, ws = 0.f;
    for (int i = lo; i < hi; ++i) {
        int s = csr_src[i];
        float w = expf(lrelu(asrc2[s] + ad));
        float2 hv = *(const float2*)&h2[(size_t)s * 2];
        n0 = fmaf(w, hv.x, n0);
        n1 = fmaf(w, hv.y, n1);
        ws += w;
    }
    float inv = 1.f / (ws + 1e-16f);
    float v0 = n0 * inv + b2[0];
    float v1 = n1 * inv + b2[1];
    float m = fmaxf(v0, v1);
    float lse = m + log1pf(expf(fminf(v0, v1) - m));
    out[(size_t)n * 2]     = v0 - lse;
    out[(size_t)n * 2 + 1] = v1 - lse;
}

extern "C" void kernel_launch(void* const* d_in, const int* in_sizes, int n_in,
                              void* d_out, int out_size, void* d_ws, size_t ws_size,
                              hipStream_t stream)
{
    const float* x     = (const float*)d_in[0];
    const int*   ei    = (const int*)d_in[1];
    const float* W1    = (const float*)d_in[2];
    const float* attS1 = (const float*)d_in[3];
    const float* attD1 = (const float*)d_in[4];
    const float* b1    = (const float*)d_in[5];
    const float* gamma = (const float*)d_in[6];
    const float* beta  = (const float*)d_in[7];
    const float* rmean = (const float*)d_in[8];
    const float* rvar  = (const float*)d_in[9];
    const float* W2    = (const float*)d_in[10];
    const float* attS2 = (const float*)d_in[11];
    const float* attD2 = (const float*)d_in[12];
    const float* b2    = (const float*)d_in[13];
    float* out = (float*)d_out;

    // workspace layout
    float* f = (float*)d_ws;
    float* asrc1 = f;                         // N*4
    float* adst1 = asrc1 + (size_t)NN * 4;    // N*4
    float* g1    = adst1 + (size_t)NN * 4;    // N*256
    float* ewp   = g1    + (size_t)NN * 256;  // E*4
    float* h2    = ewp   + (size_t)EE * 4;    // N*2
    float* asrc2 = h2    + (size_t)NN * 2;    // N
    float* adst2 = asrc2 + (size_t)NN;        // N
    int* counts  = (int*)(adst2 + (size_t)NN); // N [zeroed]
    int* offs    = counts + NN;               // N+1
    int* cursor  = offs + (NN + 1);           // N
    int* bsum    = cursor + NN;               // NB
    int* bbase   = bsum + NB;                 // NB
    int* csr_src = bbase + NB;                // E
    __half* h1   = (__half*)(csr_src + EE);   // N*256 fp16

    hipMemsetAsync(counts, 0, (size_t)NN * sizeof(int), stream);

    gemm1_kernel<<<NN / 32, 256, 0, stream>>>(x, W1, attS1, attD1, h1, asrc1, adst1);

    hist_kernel<<<(EE + 255) / 256, 256, 0, stream>>>(ei, counts);
    scan1_kernel<<<NB, 256, 0, stream>>>(counts, bsum);
    scan2_kernel<<<1, 128, 0, stream>>>(bsum, bbase, offs);
    scan3_kernel<<<NB, 256, 0, stream>>>(counts, bbase, offs);
    hipMemcpyAsync(cursor, offs, (size_t)NN * sizeof(int), hipMemcpyDeviceToDevice, stream);
    scatter_kernel<<<(EE + 255) / 256, 256, 0, stream>>>(ei, asrc1, adst1, cursor, csr_src, ewp);

    agg1_kernel<<<(NN + 3) / 4, 256, 0, stream>>>(offs, csr_src, ewp, h1, g1);

    node2_kernel<<<(NN + 3) / 4, 256, 0, stream>>>(g1, b1, gamma, beta, rmean, rvar,
                                                   W2, attS2, attD2, h2, asrc2, adst2);

    agg2_kernel<<<(NN + 255) / 256, 256, 0, stream>>>(offs, csr_src, asrc2, adst2, h2, b2, out);
}

// Round 5
// 455.659 us; speedup vs baseline: 2.1695x; 1.0923x over previous
//
#include <hip/hip_runtime.h>
#include <hip/hip_fp16.h>
#include <math.h>

#define NN 100000
#define EE 1600000
#define NEG 0.2f
#define NB 98   // ceil(NN/1024) scan blocks

__device__ __forceinline__ float lrelu(float v) { return v > 0.f ? v : NEG * v; }

__device__ __forceinline__ void fma8(const uint4& r, float w, float* acc)
{
    float2 f0 = __half22float2(*(const __half2*)&r.x);
    float2 f1 = __half22float2(*(const __half2*)&r.y);
    float2 f2 = __half22float2(*(const __half2*)&r.z);
    float2 f3 = __half22float2(*(const __half2*)&r.w);
    acc[0] = fmaf(w, f0.x, acc[0]); acc[1] = fmaf(w, f0.y, acc[1]);
    acc[2] = fmaf(w, f1.x, acc[2]); acc[3] = fmaf(w, f1.y, acc[3]);
    acc[4] = fmaf(w, f2.x, acc[4]); acc[5] = fmaf(w, f2.y, acc[5]);
    acc[6] = fmaf(w, f3.x, acc[6]); acc[7] = fmaf(w, f3.y, acc[7]);
}

// ---------------- GEMM1: h1 = x @ W1 (no bias), fused a_src1/a_dst1 ----------------
__global__ __launch_bounds__(256) void gemm1_kernel(
    const float* __restrict__ x, const float* __restrict__ W1,
    const float* __restrict__ attS1, const float* __restrict__ attD1,
    __half* __restrict__ h1, float* __restrict__ asrc1, float* __restrict__ adst1)
{
    __shared__ float xs[128][36];   // transposed x tile, padded
    const int tid  = threadIdx.x;
    const int base = blockIdx.x * 32;

    for (int t = tid; t < 32 * 128; t += 256) {
        int node = t >> 7, k = t & 127;
        xs[k][node] = x[(size_t)(base + node) * 128 + k];
    }
    __syncthreads();

    const int fg = tid & 31;   // features fg*8 .. fg*8+7
    const int ng = tid >> 5;   // nodes   ng*4 .. ng*4+3

    float acc[4][8];
#pragma unroll
    for (int i = 0; i < 4; i++) {
#pragma unroll
        for (int c = 0; c < 8; c++) acc[i][c] = 0.f;
    }

    const float* wbase = W1 + fg * 8;
    for (int k = 0; k < 128; k++) {
        float4 xv = *(const float4*)&xs[k][ng * 4];
        float4 w0 = *(const float4*)(wbase + k * 256);
        float4 w1 = *(const float4*)(wbase + k * 256 + 4);
        float xa[4] = {xv.x, xv.y, xv.z, xv.w};
        float wa[8] = {w0.x, w0.y, w0.z, w0.w, w1.x, w1.y, w1.z, w1.w};
#pragma unroll
        for (int i = 0; i < 4; i++) {
#pragma unroll
            for (int c = 0; c < 8; c++)
                acc[i][c] = fmaf(xa[i], wa[c], acc[i][c]);
        }
    }

    float attS[8], attD[8];
#pragma unroll
    for (int c = 0; c < 8; c++) { attS[c] = attS1[fg * 8 + c]; attD[c] = attD1[fg * 8 + c]; }
    const int head = fg >> 3;

#pragma unroll
    for (int i = 0; i < 4; i++) {
        int node = base + ng * 4 + i;
        __half hb[8];
#pragma unroll
        for (int c = 0; c < 8; c++) hb[c] = __float2half(acc[i][c]);
        *(float4*)&h1[(size_t)node * 256 + fg * 8] = *(float4*)hb;   // 16B packed fp16 store
        float ps = 0.f, pd = 0.f;
#pragma unroll
        for (int c = 0; c < 8; c++) { ps = fmaf(acc[i][c], attS[c], ps); pd = fmaf(acc[i][c], attD[c], pd); }
        ps += __shfl_xor(ps, 1); ps += __shfl_xor(ps, 2); ps += __shfl_xor(ps, 4);
        pd += __shfl_xor(pd, 1); pd += __shfl_xor(pd, 2); pd += __shfl_xor(pd, 4);
        if ((fg & 7) == 0) { asrc1[node * 4 + head] = ps; adst1[node * 4 + head] = pd; }
    }
}

// ---------------- CSR build ----------------
__global__ void hist_kernel(const int* __restrict__ ei, int* __restrict__ counts)
{
    int e = blockIdx.x * 256 + threadIdx.x;
    if (e >= EE) return;
    atomicAdd(&counts[ei[EE + e]], 1);
}

// phase 1: per-block (1024 elements) reduce -> bsum
__global__ __launch_bounds__(256) void scan1_kernel(const int* __restrict__ counts, int* __restrict__ bsum)
{
    __shared__ int red[256];
    int t = threadIdx.x;
    int i0 = blockIdx.x * 1024 + t * 4;
    int s = 0;
    if (i0 + 3 < NN) {
        int4 v = *(const int4*)&counts[i0];
        s = v.x + v.y + v.z + v.w;
    } else {
#pragma unroll
        for (int j = 0; j < 4; j++) { int i = i0 + j; if (i < NN) s += counts[i]; }
    }
    red[t] = s;
    __syncthreads();
    for (int off = 128; off > 0; off >>= 1) {
        if (t < off) red[t] += red[t + off];
        __syncthreads();
    }
    if (t == 0) bsum[blockIdx.x] = red[0];
}

// phase 2: single small block scans NB block sums -> exclusive bases; writes offs[NN]
__global__ void scan2_kernel(const int* __restrict__ bsum, int* __restrict__ bbase, int* __restrict__ offs)
{
    __shared__ int sh[128];
    int t = threadIdx.x;
    int v = (t < NB) ? bsum[t] : 0;
    sh[t] = v;
    __syncthreads();
    for (int off = 1; off < 128; off <<= 1) {
        int u = (t >= off) ? sh[t - off] : 0;
        __syncthreads();
        sh[t] += u;
        __syncthreads();
    }
    if (t < NB) bbase[t] = sh[t] - v;   // exclusive
    if (t == 0) offs[NN] = EE;
}

// phase 3: per-block exclusive scan of its 1024 counts + base -> offs
__global__ __launch_bounds__(256) void scan3_kernel(const int* __restrict__ counts,
                                                    const int* __restrict__ bbase,
                                                    int* __restrict__ offs)
{
    __shared__ int sh[256];
    int t = threadIdx.x;
    int i0 = blockIdx.x * 1024 + t * 4;
    int c[4];
    int s = 0;
#pragma unroll
    for (int j = 0; j < 4; j++) { int i = i0 + j; c[j] = (i < NN) ? counts[i] : 0; s += c[j]; }
    sh[t] = s;
    __syncthreads();
    for (int off = 1; off < 256; off <<= 1) {
        int u = (t >= off) ? sh[t - off] : 0;
        __syncthreads();
        sh[t] += u;
        __syncthreads();
    }
    int run = bbase[blockIdx.x] + sh[t] - s;   // exclusive within block
    if (i0 + 3 < NN) {
        int4 o;
        o.x = run; run += c[0];
        o.y = run; run += c[1];
        o.z = run; run += c[2];
        o.w = run;
        *(int4*)&offs[i0] = o;
    } else {
#pragma unroll
        for (int j = 0; j < 4; j++) { int i = i0 + j; if (i < NN) { offs[i] = run; run += c[j]; } }
    }
}

// scatter edges into CSR slots; fuse per-edge attention weight computation
__global__ void scatter_kernel(const int* __restrict__ ei,
                               const float* __restrict__ asrc1, const float* __restrict__ adst1,
                               int* __restrict__ cursor, int* __restrict__ csr_src,
                               float* __restrict__ ewp)
{
    int e = blockIdx.x * 256 + threadIdx.x;
    if (e >= EE) return;
    int s = ei[e], d = ei[EE + e];
    int pos = atomicAdd(&cursor[d], 1);
    csr_src[pos] = s;
    float4 as = *(const float4*)&asrc1[(size_t)s * 4];
    float4 ad = *(const float4*)&adst1[(size_t)d * 4];
    float4 w;
    w.x = expf(lrelu(as.x + ad.x));
    w.y = expf(lrelu(as.y + ad.y));
    w.z = expf(lrelu(as.z + ad.z));
    w.w = expf(lrelu(as.w + ad.w));
    *(float4*)&ewp[(size_t)pos * 4] = w;
}

// ---------------- layer-1 aggregation: one wave per node, 2 edges/iter + 2x unroll ----------------
// lanes 0-31 handle even-position edges, lanes 32-63 odd; each lane loads 16 B (8 fp16 feats).
// 4 rows (2 KB) in flight per wave. Cross-parity shfl_xor(32) merge at the end.
__global__ __launch_bounds__(256) void agg1_kernel(
    const int* __restrict__ offs, const int* __restrict__ csr_src,
    const float* __restrict__ ewp, const __half* __restrict__ h1,
    float* __restrict__ g1)
{
    int wid  = (blockIdx.x * 256 + threadIdx.x) >> 6;  // node
    int lane = threadIdx.x & 63;
    if (wid >= NN) return;
    int lo = offs[wid], hi = offs[wid + 1];
    const int ep   = lane >> 5;    // edge parity for this lane
    const int fl   = lane & 31;    // feature block: fl*8 .. fl*8+7
    const int head = fl >> 3;      // 64 feats/head, 8 feats/lane

    float acc[8] = {0.f, 0.f, 0.f, 0.f, 0.f, 0.f, 0.f, 0.f};
    float wsum = 0.f;

    int base = lo;
    for (; base + 3 < hi; base += 4) {
        int idx0 = base + ep;
        int idx1 = base + 2 + ep;
        int s0 = csr_src[idx0];
        int s1 = csr_src[idx1];
        float w0 = ewp[(size_t)idx0 * 4 + head];
        float w1 = ewp[(size_t)idx1 * 4 + head];
        uint4 r0 = *(const uint4*)(h1 + (size_t)s0 * 256 + fl * 8);
        uint4 r1 = *(const uint4*)(h1 + (size_t)s1 * 256 + fl * 8);
        fma8(r0, w0, acc);
        fma8(r1, w1, acc);
        wsum += w0 + w1;
    }
    for (; base < hi; base += 2) {
        int idx = base + ep;
        float w = 0.f;
        uint4 r = make_uint4(0, 0, 0, 0);
        if (idx < hi) {
            int s = csr_src[idx];
            w = ewp[(size_t)idx * 4 + head];
            r = *(const uint4*)(h1 + (size_t)s * 256 + fl * 8);
        }
        fma8(r, w, acc);
        wsum += w;
    }

#pragma unroll
    for (int j = 0; j < 8; j++) acc[j] += __shfl_xor(acc[j], 32);
    wsum += __shfl_xor(wsum, 32);

    if (lane < 32) {
        float inv = 1.f / (wsum + 1e-16f);
        *(float4*)&g1[(size_t)wid * 256 + fl * 8]     = make_float4(acc[0] * inv, acc[1] * inv, acc[2] * inv, acc[3] * inv);
        *(float4*)&g1[(size_t)wid * 256 + fl * 8 + 4] = make_float4(acc[4] * inv, acc[5] * inv, acc[6] * inv, acc[7] * inv);
    }
}

// ---------------- node2: bias + BN + ELU + GEMM2(256->2) + att2 dots (wave/node) ----------------
__global__ __launch_bounds__(256) void node2_kernel(
    const float* __restrict__ g1, const float* __restrict__ b1,
    const float* __restrict__ gamma, const float* __restrict__ beta,
    const float* __restrict__ rmean, const float* __restrict__ rvar,
    const float* __restrict__ W2, const float* __restrict__ attS2, const float* __restrict__ attD2,
    float* __restrict__ h2, float* __restrict__ asrc2, float* __restrict__ adst2)
{
    int n    = blockIdx.x * 4 + (threadIdx.x >> 6);
    int lane = threadIdx.x & 63;
    if (n >= NN) return;
    int f4 = lane * 4;
    float4 v  = *(const float4*)&g1[(size_t)n * 256 + f4];
    float4 bv = *(const float4*)&b1[f4];
    float4 rm = *(const float4*)&rmean[f4];
    float4 rv = *(const float4*)&rvar[f4];
    float4 gm = *(const float4*)&gamma[f4];
    float4 bt = *(const float4*)&beta[f4];
    float va[4] = {v.x, v.y, v.z, v.w};
    float ba[4] = {bv.x, bv.y, bv.z, bv.w};
    float rma[4] = {rm.x, rm.y, rm.z, rm.w};
    float rva[4] = {rv.x, rv.y, rv.z, rv.w};
    float gma[4] = {gm.x, gm.y, gm.z, gm.w};
    float bta[4] = {bt.x, bt.y, bt.z, bt.w};
    float t[4];
#pragma unroll
    for (int j = 0; j < 4; j++) {
        float u = (va[j] + ba[j] - rma[j]) * rsqrtf(rva[j] + 1e-5f) * gma[j] + bta[j];
        t[j] = u > 0.f ? u : expm1f(u);
    }
    float4 w01 = *(const float4*)&W2[(size_t)f4 * 2];
    float4 w23 = *(const float4*)&W2[(size_t)f4 * 2 + 4];
    float c0 = t[0] * w01.x + t[1] * w01.z + t[2] * w23.x + t[3] * w23.z;
    float c1 = t[0] * w01.y + t[1] * w01.w + t[2] * w23.y + t[3] * w23.w;
    for (int off = 1; off < 64; off <<= 1) {
        c0 += __shfl_xor(c0, off);
        c1 += __shfl_xor(c1, off);
    }
    if (lane == 0) {
        h2[(size_t)n * 2]     = c0;
        h2[(size_t)n * 2 + 1] = c1;
        asrc2[n] = c0 * attS2[0] + c1 * attS2[1];
        adst2[n] = c0 * attD2[0] + c1 * attD2[1];
    }
}

// ---------------- layer-2 aggregation via CSR + fused bias/log_softmax ----------------
__global__ void agg2_kernel(const int* __restrict__ offs, const int* __restrict__ csr_src,
                            const float* __restrict__ asrc2, const float* __restrict__ adst2,
                            const float* __restrict__ h2, const float* __restrict__ b2,
                            float* __restrict__ out)
{
    int n = blockIdx.x * 256 + threadIdx.x;
    if (n >= NN) return;
    int lo = offs[n], hi = offs[n + 1];
    float ad = adst2[n];
    float n0 = 0.f, n1 = 0.f, ws = 0.f;
    for (int i = lo; i < hi; ++i) {
        int s = csr_src[i];
        float w = expf(lrelu(asrc2[s] + ad));
        float2 hv = *(const float2*)&h2[(size_t)s * 2];
        n0 = fmaf(w, hv.x, n0);
        n1 = fmaf(w, hv.y, n1);
        ws += w;
    }
    float inv = 1.f / (ws + 1e-16f);
    float v0 = n0 * inv + b2[0];
    float v1 = n1 * inv + b2[1];
    float m = fmaxf(v0, v1);
    float lse = m + log1pf(expf(fminf(v0, v1) - m));
    out[(size_t)n * 2]     = v0 - lse;
    out[(size_t)n * 2 + 1] = v1 - lse;
}

extern "C" void kernel_launch(void* const* d_in, const int* in_sizes, int n_in,
                              void* d_out, int out_size, void* d_ws, size_t ws_size,
                              hipStream_t stream)
{
    const float* x     = (const float*)d_in[0];
    const int*   ei    = (const int*)d_in[1];
    const float* W1    = (const float*)d_in[2];
    const float* attS1 = (const float*)d_in[3];
    const float* attD1 = (const float*)d_in[4];
    const float* b1    = (const float*)d_in[5];
    const float* gamma = (const float*)d_in[6];
    const float* beta  = (const float*)d_in[7];
    const float* rmean = (const float*)d_in[8];
    const float* rvar  = (const float*)d_in[9];
    const float* W2    = (const float*)d_in[10];
    const float* attS2 = (const float*)d_in[11];
    const float* attD2 = (const float*)d_in[12];
    const float* b2    = (const float*)d_in[13];
    float* out = (float*)d_out;

    // workspace layout: h1 first (16B-aligned for uint4 row loads)
    float* f = (float*)d_ws;
    __half* h1   = (__half*)f;                 // N*256 fp16 = N*128 floats
    float* asrc1 = f + (size_t)NN * 128;       // N*4
    float* adst1 = asrc1 + (size_t)NN * 4;     // N*4
    float* g1    = adst1 + (size_t)NN * 4;     // N*256
    float* ewp   = g1    + (size_t)NN * 256;   // E*4
    float* h2    = ewp   + (size_t)EE * 4;     // N*2
    float* asrc2 = h2    + (size_t)NN * 2;     // N
    float* adst2 = asrc2 + (size_t)NN;         // N
    int* counts  = (int*)(adst2 + (size_t)NN); // N [zeroed]
    int* offs    = counts + NN;                // N+1
    int* cursor  = offs + (NN + 1);            // N
    int* bsum    = cursor + NN;                // NB
    int* bbase   = bsum + NB;                  // NB
    int* csr_src = bbase + NB;                 // E

    hipMemsetAsync(counts, 0, (size_t)NN * sizeof(int), stream);

    gemm1_kernel<<<NN / 32, 256, 0, stream>>>(x, W1, attS1, attD1, h1, asrc1, adst1);

    hist_kernel<<<(EE + 255) / 256, 256, 0, stream>>>(ei, counts);
    scan1_kernel<<<NB, 256, 0, stream>>>(counts, bsum);
    scan2_kernel<<<1, 128, 0, stream>>>(bsum, bbase, offs);
    scan3_kernel<<<NB, 256, 0, stream>>>(counts, bbase, offs);
    hipMemcpyAsync(cursor, offs, (size_t)NN * sizeof(int), hipMemcpyDeviceToDevice, stream);
    scatter_kernel<<<(EE + 255) / 256, 256, 0, stream>>>(ei, asrc1, adst1, cursor, csr_src, ewp);

    agg1_kernel<<<(NN + 3) / 4, 256, 0, stream>>>(offs, csr_src, ewp, h1, g1);

    node2_kernel<<<(NN + 3) / 4, 256, 0, stream>>>(g1, b1, gamma, beta, rmean, rvar,
                                                   W2, attS2, attD2, h2, asrc2, adst2);

    agg2_kernel<<<(NN + 255) / 256, 256, 0, stream>>>(offs, csr_src, asrc2, adst2, h2, b2, out);
}

// Round 6
// 373.794 us; speedup vs baseline: 2.6446x; 1.2190x over previous
//
#include <hip/hip_runtime.h>
#include <hip/hip_fp16.h>
#include <math.h>

#define NN 100000
#define EE 1600000
#define NEG 0.2f
#define NB 98     // ceil(NN/1024) scan blocks
#define STRIP 128 // nodes per gemm1 block

typedef _Float16 fh8 __attribute__((ext_vector_type(8)));
typedef float f32x4 __attribute__((ext_vector_type(4)));

__device__ __forceinline__ float lrelu(float v) { return v > 0.f ? v : NEG * v; }

__device__ __forceinline__ void fma8(const uint4& r, float w, float* acc)
{
    float2 f0 = __half22float2(*(const __half2*)&r.x);
    float2 f1 = __half22float2(*(const __half2*)&r.y);
    float2 f2 = __half22float2(*(const __half2*)&r.z);
    float2 f3 = __half22float2(*(const __half2*)&r.w);
    acc[0] = fmaf(w, f0.x, acc[0]); acc[1] = fmaf(w, f0.y, acc[1]);
    acc[2] = fmaf(w, f1.x, acc[2]); acc[3] = fmaf(w, f1.y, acc[3]);
    acc[4] = fmaf(w, f2.x, acc[4]); acc[5] = fmaf(w, f2.y, acc[5]);
    acc[6] = fmaf(w, f3.x, acc[6]); acc[7] = fmaf(w, f3.y, acc[7]);
}

// ---------------- pack W1 into MFMA A-fragment order (fp16) ----------------
// frag id = (w*4 + ft)*4 + kk ; lane l holds A[m = l&15][k = kk*32 + (l>>4)*8 + i]
// where A[m][k] = W1[k][w*64 + ft*16 + m]
__global__ void packW1_kernel(const float* __restrict__ W1, _Float16* __restrict__ W1f)
{
    int t = blockIdx.x * 256 + threadIdx.x;   // 0 .. 4095
    if (t >= 64 * 64) return;
    int l = t & 63, frag = t >> 6;
    int kk = frag & 3, ft = (frag >> 2) & 3, w = frag >> 4;
    int feat = w * 64 + ft * 16 + (l & 15);
    int kbase = kk * 32 + (l >> 4) * 8;
    _Float16 v[8];
#pragma unroll
    for (int i = 0; i < 8; i++) v[i] = (_Float16)W1[(size_t)(kbase + i) * 256 + feat];
    *(fh8*)&W1f[(size_t)t * 8] = *(fh8*)v;
}

// ---------------- GEMM1 via MFMA: h1 = x @ W1 (fp16 in/out, fp32 accum) ----------------
// 4 waves/block; wave w = head w owns feats w*64..w*64+63 (4 m-tiles).
// Per block: stage STRIP nodes of x as fp16 in LDS, iterate STRIP/16 node-groups.
__global__ __launch_bounds__(256) void gemm1_mfma(
    const float* __restrict__ x, const _Float16* __restrict__ W1f,
    const float* __restrict__ attS1, const float* __restrict__ attD1,
    __half* __restrict__ h1, float* __restrict__ asrc1, float* __restrict__ adst1)
{
    __shared__ _Float16 xh[STRIP][136];   // padded row: 272 B -> 2-way LDS aliasing (free)
    const int tid  = threadIdx.x;
    const int lane = tid & 63;
    const int w    = tid >> 6;            // wave id == head id
    const int base = blockIdx.x * STRIP;

    // stage x (fp32 -> fp16): 2 passes x 256 threads; each slot = (node, 32-k chunk)
#pragma unroll
    for (int it = 0; it < 2; ++it) {
        int slot = tid + it * 256;        // 0..511
        int node = slot >> 2;
        int k0   = (slot & 3) * 32;
        int gnode = base + node;
        float4 buf[8];
        if (gnode < NN) {
            const float4* src = (const float4*)(x + (size_t)gnode * 128 + k0);
#pragma unroll
            for (int j = 0; j < 8; j++) buf[j] = src[j];
        } else {
#pragma unroll
            for (int j = 0; j < 8; j++) buf[j] = make_float4(0.f, 0.f, 0.f, 0.f);
        }
        _Float16* dst = &xh[node][k0];
#pragma unroll
        for (int j = 0; j < 8; j++) {
            dst[j * 4 + 0] = (_Float16)buf[j].x;
            dst[j * 4 + 1] = (_Float16)buf[j].y;
            dst[j * 4 + 2] = (_Float16)buf[j].z;
            dst[j * 4 + 3] = (_Float16)buf[j].w;
        }
    }
    __syncthreads();

    // A-fragments (W1 slice for this head): 16 x 16B, stay in registers
    fh8 afrag[4][4];
    const fh8* wf = (const fh8*)W1f;
#pragma unroll
    for (int ft = 0; ft < 4; ft++)
#pragma unroll
        for (int kk = 0; kk < 4; kk++)
            afrag[ft][kk] = wf[((w * 4 + ft) * 4 + kk) * 64 + lane];

    const int nrow = lane & 15;   // node within group (D col)
    const int kq   = lane >> 4;

    // attention vectors for this lane's 16 feats
    float attSv[4][4], attDv[4][4];
#pragma unroll
    for (int ft = 0; ft < 4; ft++)
#pragma unroll
        for (int r = 0; r < 4; r++) {
            int feat = w * 64 + ft * 16 + kq * 4 + r;
            attSv[ft][r] = attS1[feat];
            attDv[ft][r] = attD1[feat];
        }

    for (int g = 0; g < STRIP / 16; ++g) {
        fh8 b[4];
#pragma unroll
        for (int kk = 0; kk < 4; kk++)
            b[kk] = *(const fh8*)&xh[g * 16 + nrow][kk * 32 + kq * 8];

        f32x4 d[4];
#pragma unroll
        for (int ft = 0; ft < 4; ft++) {
            d[ft] = (f32x4){0.f, 0.f, 0.f, 0.f};
#pragma unroll
            for (int kk = 0; kk < 4; kk++)
                d[ft] = __builtin_amdgcn_mfma_f32_16x16x32_f16(afrag[ft][kk], b[kk], d[ft], 0, 0, 0);
        }

        int gnode = base + g * 16 + nrow;
        if (gnode < NN) {
            float ps = 0.f, pd = 0.f;
#pragma unroll
            for (int ft = 0; ft < 4; ft++) {
                __half hb[4];
#pragma unroll
                for (int r = 0; r < 4; r++) {
                    float v = d[ft][r];
                    hb[r] = __float2half(v);
                    ps = fmaf(v, attSv[ft][r], ps);
                    pd = fmaf(v, attDv[ft][r], pd);
                }
                *(float2*)&h1[(size_t)gnode * 256 + w * 64 + ft * 16 + kq * 4] = *(float2*)hb;
            }
            ps += __shfl_xor(ps, 16); ps += __shfl_xor(ps, 32);
            pd += __shfl_xor(pd, 16); pd += __shfl_xor(pd, 32);
            if (kq == 0) { asrc1[gnode * 4 + w] = ps; adst1[gnode * 4 + w] = pd; }
        }
    }
}

// ---------------- CSR build ----------------
__global__ void hist_kernel(const int* __restrict__ ei, int* __restrict__ counts)
{
    int e = blockIdx.x * 256 + threadIdx.x;
    if (e >= EE) return;
    atomicAdd(&counts[ei[EE + e]], 1);
}

__global__ __launch_bounds__(256) void scan1_kernel(const int* __restrict__ counts, int* __restrict__ bsum)
{
    __shared__ int red[256];
    int t = threadIdx.x;
    int i0 = blockIdx.x * 1024 + t * 4;
    int s = 0;
    if (i0 + 3 < NN) {
        int4 v = *(const int4*)&counts[i0];
        s = v.x + v.y + v.z + v.w;
    } else {
#pragma unroll
        for (int j = 0; j < 4; j++) { int i = i0 + j; if (i < NN) s += counts[i]; }
    }
    red[t] = s;
    __syncthreads();
    for (int off = 128; off > 0; off >>= 1) {
        if (t < off) red[t] += red[t + off];
        __syncthreads();
    }
    if (t == 0) bsum[blockIdx.x] = red[0];
}

__global__ void scan2_kernel(const int* __restrict__ bsum, int* __restrict__ bbase, int* __restrict__ offs)
{
    __shared__ int sh[128];
    int t = threadIdx.x;
    int v = (t < NB) ? bsum[t] : 0;
    sh[t] = v;
    __syncthreads();
    for (int off = 1; off < 128; off <<= 1) {
        int u = (t >= off) ? sh[t - off] : 0;
        __syncthreads();
        sh[t] += u;
        __syncthreads();
    }
    if (t < NB) bbase[t] = sh[t] - v;
    if (t == 0) offs[NN] = EE;
}

__global__ __launch_bounds__(256) void scan3_kernel(const int* __restrict__ counts,
                                                    const int* __restrict__ bbase,
                                                    int* __restrict__ offs)
{
    __shared__ int sh[256];
    int t = threadIdx.x;
    int i0 = blockIdx.x * 1024 + t * 4;
    int c[4];
    int s = 0;
#pragma unroll
    for (int j = 0; j < 4; j++) { int i = i0 + j; c[j] = (i < NN) ? counts[i] : 0; s += c[j]; }
    sh[t] = s;
    __syncthreads();
    for (int off = 1; off < 256; off <<= 1) {
        int u = (t >= off) ? sh[t - off] : 0;
        __syncthreads();
        sh[t] += u;
        __syncthreads();
    }
    int run = bbase[blockIdx.x] + sh[t] - s;
    if (i0 + 3 < NN) {
        int4 o;
        o.x = run; run += c[0];
        o.y = run; run += c[1];
        o.z = run; run += c[2];
        o.w = run;
        *(int4*)&offs[i0] = o;
    } else {
#pragma unroll
        for (int j = 0; j < 4; j++) { int i = i0 + j; if (i < NN) { offs[i] = run; run += c[j]; } }
    }
}

__global__ void scatter_kernel(const int* __restrict__ ei,
                               const float* __restrict__ asrc1, const float* __restrict__ adst1,
                               int* __restrict__ cursor, int* __restrict__ csr_src,
                               float* __restrict__ ewp)
{
    int e = blockIdx.x * 256 + threadIdx.x;
    if (e >= EE) return;
    int s = ei[e], d = ei[EE + e];
    int pos = atomicAdd(&cursor[d], 1);
    csr_src[pos] = s;
    float4 as = *(const float4*)&asrc1[(size_t)s * 4];
    float4 ad = *(const float4*)&adst1[(size_t)d * 4];
    float4 w;
    w.x = expf(lrelu(as.x + ad.x));
    w.y = expf(lrelu(as.y + ad.y));
    w.z = expf(lrelu(as.z + ad.z));
    w.w = expf(lrelu(as.w + ad.w));
    *(float4*)&ewp[(size_t)pos * 4] = w;
}

// ---------------- layer-1 aggregation: one wave per node, 2 edges/iter + 2x unroll ----------------
__global__ __launch_bounds__(256) void agg1_kernel(
    const int* __restrict__ offs, const int* __restrict__ csr_src,
    const float* __restrict__ ewp, const __half* __restrict__ h1,
    float* __restrict__ g1)
{
    int wid  = (blockIdx.x * 256 + threadIdx.x) >> 6;
    int lane = threadIdx.x & 63;
    if (wid >= NN) return;
    int lo = offs[wid], hi = offs[wid + 1];
    const int ep   = lane >> 5;
    const int fl   = lane & 31;
    const int head = fl >> 3;

    float acc[8] = {0.f, 0.f, 0.f, 0.f, 0.f, 0.f, 0.f, 0.f};
    float wsum = 0.f;

    int base = lo;
    for (; base + 3 < hi; base += 4) {
        int idx0 = base + ep;
        int idx1 = base + 2 + ep;
        int s0 = csr_src[idx0];
        int s1 = csr_src[idx1];
        float w0 = ewp[(size_t)idx0 * 4 + head];
        float w1 = ewp[(size_t)idx1 * 4 + head];
        uint4 r0 = *(const uint4*)(h1 + (size_t)s0 * 256 + fl * 8);
        uint4 r1 = *(const uint4*)(h1 + (size_t)s1 * 256 + fl * 8);
        fma8(r0, w0, acc);
        fma8(r1, w1, acc);
        wsum += w0 + w1;
    }
    for (; base < hi; base += 2) {
        int idx = base + ep;
        float w = 0.f;
        uint4 r = make_uint4(0, 0, 0, 0);
        if (idx < hi) {
            int s = csr_src[idx];
            w = ewp[(size_t)idx * 4 + head];
            r = *(const uint4*)(h1 + (size_t)s * 256 + fl * 8);
        }
        fma8(r, w, acc);
        wsum += w;
    }

#pragma unroll
    for (int j = 0; j < 8; j++) acc[j] += __shfl_xor(acc[j], 32);
    wsum += __shfl_xor(wsum, 32);

    if (lane < 32) {
        float inv = 1.f / (wsum + 1e-16f);
        *(float4*)&g1[(size_t)wid * 256 + fl * 8]     = make_float4(acc[0] * inv, acc[1] * inv, acc[2] * inv, acc[3] * inv);
        *(float4*)&g1[(size_t)wid * 256 + fl * 8 + 4] = make_float4(acc[4] * inv, acc[5] * inv, acc[6] * inv, acc[7] * inv);
    }
}

// ---------------- node2: bias + BN + ELU + GEMM2(256->2) + att2 dots (wave/node) ----------------
__global__ __launch_bounds__(256) void node2_kernel(
    const float* __restrict__ g1, const float* __restrict__ b1,
    const float* __restrict__ gamma, const float* __restrict__ beta,
    const float* __restrict__ rmean, const float* __restrict__ rvar,
    const float* __restrict__ W2, const float* __restrict__ attS2, const float* __restrict__ attD2,
    float* __restrict__ h2, float* __restrict__ asrc2, float* __restrict__ adst2)
{
    int n    = blockIdx.x * 4 + (threadIdx.x >> 6);
    int lane = threadIdx.x & 63;
    if (n >= NN) return;
    int f4 = lane * 4;
    float4 v  = *(const float4*)&g1[(size_t)n * 256 + f4];
    float4 bv = *(const float4*)&b1[f4];
    float4 rm = *(const float4*)&rmean[f4];
    float4 rv = *(const float4*)&rvar[f4];
    float4 gm = *(const float4*)&gamma[f4];
    float4 bt = *(const float4*)&beta[f4];
    float va[4] = {v.x, v.y, v.z, v.w};
    float ba[4] = {bv.x, bv.y, bv.z, bv.w};
    float rma[4] = {rm.x, rm.y, rm.z, rm.w};
    float rva[4] = {rv.x, rv.y, rv.z, rv.w};
    float gma[4] = {gm.x, gm.y, gm.z, gm.w};
    float bta[4] = {bt.x, bt.y, bt.z, bt.w};
    float t[4];
#pragma unroll
    for (int j = 0; j < 4; j++) {
        float u = (va[j] + ba[j] - rma[j]) * rsqrtf(rva[j] + 1e-5f) * gma[j] + bta[j];
        t[j] = u > 0.f ? u : expm1f(u);
    }
    float4 w01 = *(const float4*)&W2[(size_t)f4 * 2];
    float4 w23 = *(const float4*)&W2[(size_t)f4 * 2 + 4];
    float c0 = t[0] * w01.x + t[1] * w01.z + t[2] * w23.x + t[3] * w23.z;
    float c1 = t[0] * w01.y + t[1] * w01.w + t[2] * w23.y + t[3] * w23.w;
    for (int off = 1; off < 64; off <<= 1) {
        c0 += __shfl_xor(c0, off);
        c1 += __shfl_xor(c1, off);
    }
    if (lane == 0) {
        h2[(size_t)n * 2]     = c0;
        h2[(size_t)n * 2 + 1] = c1;
        asrc2[n] = c0 * attS2[0] + c1 * attS2[1];
        adst2[n] = c0 * attD2[0] + c1 * attD2[1];
    }
}

// ---------------- layer-2 aggregation via CSR + fused bias/log_softmax ----------------
__global__ void agg2_kernel(const int* __restrict__ offs, const int* __restrict__ csr_src,
                            const float* __restrict__ asrc2, const float* __restrict__ adst2,
                            const float* __restrict__ h2, const float* __restrict__ b2,
                            float* __restrict__ out)
{
    int n = blockIdx.x * 256 + threadIdx.x;
    if (n >= NN) return;
    int lo = offs[n], hi = offs[n + 1];
    float ad = adst2[n];
    float n0 = 0.f, n1 = 0.f, ws = 0.f;
    for (int i = lo; i < hi; ++i) {
        int s = csr_src[i];
        float w = expf(lrelu(asrc2[s] + ad));
        float2 hv = *(const float2*)&h2[(size_t)s * 2];
        n0 = fmaf(w, hv.x, n0);
        n1 = fmaf(w, hv.y, n1);
        ws += w;
    }
    float inv = 1.f / (ws + 1e-16f);
    float v0 = n0 * inv + b2[0];
    float v1 = n1 * inv + b2[1];
    float m = fmaxf(v0, v1);
    float lse = m + log1pf(expf(fminf(v0, v1) - m));
    out[(size_t)n * 2]     = v0 - lse;
    out[(size_t)n * 2 + 1] = v1 - lse;
}

extern "C" void kernel_launch(void* const* d_in, const int* in_sizes, int n_in,
                              void* d_out, int out_size, void* d_ws, size_t ws_size,
                              hipStream_t stream)
{
    const float* x     = (const float*)d_in[0];
    const int*   ei    = (const int*)d_in[1];
    const float* W1    = (const float*)d_in[2];
    const float* attS1 = (const float*)d_in[3];
    const float* attD1 = (const float*)d_in[4];
    const float* b1    = (const float*)d_in[5];
    const float* gamma = (const float*)d_in[6];
    const float* beta  = (const float*)d_in[7];
    const float* rmean = (const float*)d_in[8];
    const float* rvar  = (const float*)d_in[9];
    const float* W2    = (const float*)d_in[10];
    const float* attS2 = (const float*)d_in[11];
    const float* attD2 = (const float*)d_in[12];
    const float* b2    = (const float*)d_in[13];
    float* out = (float*)d_out;

    // workspace layout: h1 first (16B-aligned for uint4 row loads)
    float* f = (float*)d_ws;
    __half* h1   = (__half*)f;                 // N*256 fp16 = N*128 floats
    float* asrc1 = f + (size_t)NN * 128;       // N*4
    float* adst1 = asrc1 + (size_t)NN * 4;     // N*4
    _Float16* W1f = (_Float16*)(adst1 + (size_t)NN * 4);  // 32768 halfs = 16384 floats
    float* g1    = adst1 + (size_t)NN * 4 + 16384;        // N*256
    float* ewp   = g1    + (size_t)NN * 256;   // E*4
    float* h2    = ewp   + (size_t)EE * 4;     // N*2
    float* asrc2 = h2    + (size_t)NN * 2;     // N
    float* adst2 = asrc2 + (size_t)NN;         // N
    int* counts  = (int*)(adst2 + (size_t)NN); // N [zeroed]
    int* offs    = counts + NN;                // N+1
    int* cursor  = offs + (NN + 1);            // N
    int* bsum    = cursor + NN;                // NB
    int* bbase   = bsum + NB;                  // NB
    int* csr_src = bbase + NB;                 // E

    hipMemsetAsync(counts, 0, (size_t)NN * sizeof(int), stream);

    packW1_kernel<<<16, 256, 0, stream>>>(W1, W1f);
    gemm1_mfma<<<(NN + STRIP - 1) / STRIP, 256, 0, stream>>>(x, W1f, attS1, attD1, h1, asrc1, adst1);

    hist_kernel<<<(EE + 255) / 256, 256, 0, stream>>>(ei, counts);
    scan1_kernel<<<NB, 256, 0, stream>>>(counts, bsum);
    scan2_kernel<<<1, 128, 0, stream>>>(bsum, bbase, offs);
    scan3_kernel<<<NB, 256, 0, stream>>>(counts, bbase, offs);
    hipMemcpyAsync(cursor, offs, (size_t)NN * sizeof(int), hipMemcpyDeviceToDevice, stream);
    scatter_kernel<<<(EE + 255) / 256, 256, 0, stream>>>(ei, asrc1, adst1, cursor, csr_src, ewp);

    agg1_kernel<<<(NN + 3) / 4, 256, 0, stream>>>(offs, csr_src, ewp, h1, g1);

    node2_kernel<<<(NN + 3) / 4, 256, 0, stream>>>(g1, b1, gamma, beta, rmean, rvar,
                                                   W2, attS2, attD2, h2, asrc2, adst2);

    agg2_kernel<<<(NN + 255) / 256, 256, 0, stream>>>(offs, csr_src, asrc2, adst2, h2, b2, out);
}